// Round 7
// baseline (195.623 us; speedup 1.0000x reference)
//
#include <hip/hip_runtime.h>
#include <hip/hip_bf16.h>

typedef __attribute__((ext_vector_type(8))) short short8;
typedef __attribute__((ext_vector_type(4))) float floatx4;
typedef unsigned short ushort_t;
typedef unsigned int uint_t;

#define DOUT   256
#define KEXT   896          // 320 + 320 + 224 + 3 bias rows + zero pad to 896
#define NTOK   16384
#define WG_BLKS 56          // 2 nblk x 28 kc
#define U_BLKS  225

static __device__ inline ushort_t f2bf(float f) {
    union { float f; uint_t u; } a; a.f = f;
    uint_t u = a.u;
    return (ushort_t)((u + 0x7FFFu + ((u >> 16) & 1u)) >> 16);
}
static __device__ inline uint_t pack2bf(float x, float y) {
    __hip_bfloat162 h = __float22bfloat162_rn(make_float2(x, y));
    return *(uint_t*)&h;
}
static __device__ inline void gload_lds16(const void* g, void* l) {
    __builtin_amdgcn_global_load_lds(
        (const __attribute__((address_space(1))) void*)g,
        (__attribute__((address_space(3))) void*)l, 16, 0, 0);
}

// ---------------------------------------------------------------------------
// Prep. blocks [0,56): Wg staging-linear B chunks — for (nblk,kc,i,lane):
//   Wg[(((nblk*28+kc)*8+i)*64+lane)*8 + j] = bf16(W_ext[kc*32+(lane&3)*8+j]
//                                                     [nblk*128+i*16+(lane>>2)])
//   W_ext rows: [0,300)=W0, [320,620)=W1, [640,840)=W2, 864..866=b0..b2, else 0.
// blocks [56,56+225): u[k]=W_ext[k,:].Wa (zero-padded to 896); lb[n]=b_n.Wa+ba
// ---------------------------------------------------------------------------
__global__ __launch_bounds__(256) void k_prep(
    const float* __restrict__ W0, const float* __restrict__ W1,
    const float* __restrict__ W2,
    const float* __restrict__ b0, const float* __restrict__ b1,
    const float* __restrict__ b2,
    const float* __restrict__ Wa, const float* __restrict__ ba,
    float* __restrict__ u, float* __restrict__ lb, ushort_t* __restrict__ Wg)
{
    int tid = threadIdx.x;
    if (blockIdx.x < WG_BLKS) {
        __shared__ ushort_t tile[32][130];
        int nblk = blockIdx.x / 28, kc = blockIdx.x % 28;
        for (int idx = tid; idx < 1024; idx += 256) {
            int kk = idx >> 5, c4 = idx & 31;
            int kp = kc * 32 + kk;
            int col = nblk * 128 + c4 * 4;
            float4 v = make_float4(0.f, 0.f, 0.f, 0.f);
            if (kp < 300)                    v = *(const float4*)(W0 + (size_t)kp * DOUT + col);
            else if (kp >= 320 && kp < 620)  v = *(const float4*)(W1 + (size_t)(kp - 320) * DOUT + col);
            else if (kp >= 640 && kp < 840)  v = *(const float4*)(W2 + (size_t)(kp - 640) * DOUT + col);
            else if (kp == 864)              v = *(const float4*)(b0 + col);
            else if (kp == 865)              v = *(const float4*)(b1 + col);
            else if (kp == 866)              v = *(const float4*)(b2 + col);
            tile[kk][c4 * 4 + 0] = f2bf(v.x);
            tile[kk][c4 * 4 + 1] = f2bf(v.y);
            tile[kk][c4 * 4 + 2] = f2bf(v.z);
            tile[kk][c4 * 4 + 3] = f2bf(v.w);
        }
        __syncthreads();
        for (int t = tid; t < 512; t += 256) {
            int i = t >> 6, l = t & 63;
            int nl = i * 16 + (l >> 2), kj = (l & 3) * 8;
            union { uint4 v; ushort_t s[8]; } p;
            #pragma unroll
            for (int j = 0; j < 8; ++j) p.s[j] = tile[kj + j][nl];
            *(uint4*)(Wg + (((size_t)(nblk * 28 + kc) * 8 + i) * 64 + l) * 8) = p.v;
        }
    } else {
        int lane = tid & 63;
        int w = tid >> 6;
        int kp = (blockIdx.x - WG_BLKS) * 4 + w;   // 0..899
        if (kp > 898) return;
        const float* row = nullptr;
        if (kp < 320)       { if (kp < 300) row = W0 + kp * DOUT; }
        else if (kp < 640)  { int o = kp - 320; if (o < 300) row = W1 + o * DOUT; }
        else if (kp < 864)  { int o = kp - 640; if (o < 200) row = W2 + o * DOUT; }
        else if (kp >= 896) { int n = kp - 896; row = (n == 0) ? b0 : ((n == 1) ? b1 : b2); }
        float acc = 0.f;
        if (row) {
            #pragma unroll
            for (int j = lane; j < DOUT; j += 64)
                acc += row[j] * Wa[j];
        }
        for (int off = 32; off > 0; off >>= 1) acc += __shfl_down(acc, off);
        if (lane == 0) {
            if (kp < 896) u[kp] = acc;
            else          lb[kp - 896] = acc + ba[0];
        }
    }
}

// ---------------------------------------------------------------------------
// Gather: 32 lanes/token, 8 tokens/block (256 thr), 2048 blocks, no LDS,
// no barriers -> max TLP. Writes alpha-scaled bf16 row (K=896, alpha at
// cols 864..866 for the bias rows) to Xg.
// ---------------------------------------------------------------------------
__global__ __launch_bounds__(256, 8) void k_gather(
    const int* __restrict__ ids,
    const float* __restrict__ E0, const float* __restrict__ E1,
    const float* __restrict__ E2,
    const float* __restrict__ u, const float* __restrict__ lb,
    ushort_t* __restrict__ Xg)
{
    int tid = threadIdx.x;
    int trow = tid >> 5, sub = tid & 31;
    int tok = blockIdx.x * 8 + trow;
    int id = ids[tok];
    const float4* p0 = (const float4*)E0 + (size_t)id * 75;
    const float4* p1 = (const float4*)E1 + (size_t)id * 75;
    const float4* p2 = (const float4*)E2 + (size_t)id * 50;
    float4 z4 = make_float4(0.f, 0.f, 0.f, 0.f);

    float4 g0 = p0[sub], g1 = p0[32 + sub], g2 = (sub < 11) ? p0[64 + sub] : z4;
    float4 g3 = p1[sub], g4 = p1[32 + sub], g5 = (sub < 11) ? p1[64 + sub] : z4;
    float4 g6 = p2[sub], g7 = (sub < 18) ? p2[32 + sub] : z4;

    // fp32 logit partials (u pads are zero; zeroed granules contribute 0)
    float l0, l1, l2;
    {
        float4 ua = *(const float4*)(u + 4 * sub);
        float4 ub = *(const float4*)(u + 128 + 4 * sub);
        float4 uc = *(const float4*)(u + 256 + 4 * sub);
        l0 = g0.x * ua.x + g0.y * ua.y + g0.z * ua.z + g0.w * ua.w
           + g1.x * ub.x + g1.y * ub.y + g1.z * ub.z + g1.w * ub.w
           + g2.x * uc.x + g2.y * uc.y + g2.z * uc.z + g2.w * uc.w;
    }
    {
        float4 ua = *(const float4*)(u + 320 + 4 * sub);
        float4 ub = *(const float4*)(u + 448 + 4 * sub);
        float4 uc = *(const float4*)(u + 576 + 4 * sub);
        l1 = g3.x * ua.x + g3.y * ua.y + g3.z * ua.z + g3.w * ua.w
           + g4.x * ub.x + g4.y * ub.y + g4.z * ub.z + g4.w * ub.w
           + g5.x * uc.x + g5.y * uc.y + g5.z * uc.z + g5.w * uc.w;
    }
    {
        float4 ua = *(const float4*)(u + 640 + 4 * sub);
        float4 ub = *(const float4*)(u + 768 + 4 * sub);
        l2 = g6.x * ua.x + g6.y * ua.y + g6.z * ua.z + g6.w * ua.w
           + g7.x * ub.x + g7.y * ub.y + g7.z * ub.z + g7.w * ub.w;
    }
    // butterfly over the token's 32 lanes (xor<32 never crosses the 32-block)
    #pragma unroll
    for (int m = 1; m < 32; m <<= 1) {
        l0 += __shfl_xor(l0, m);
        l1 += __shfl_xor(l1, m);
        l2 += __shfl_xor(l2, m);
    }
    l0 += lb[0]; l1 += lb[1]; l2 += lb[2];
    float mx = fmaxf(l0, fmaxf(l1, l2));
    float e0 = __expf(l0 - mx), e1 = __expf(l1 - mx), e2 = __expf(l2 - mx);
    float inv = 1.f / (e0 + e1 + e2);
    float a0 = e0 * inv, a1 = e1 * inv, a2 = e2 * inv;

    uint2* Xrow = (uint2*)(Xg + (size_t)tok * KEXT);
    #define PK(G, A) make_uint2(pack2bf((A) * (G).x, (A) * (G).y), pack2bf((A) * (G).z, (A) * (G).w))
    Xrow[sub]       = PK(g0, a0);
    Xrow[32 + sub]  = PK(g1, a0);
    if (sub < 16) Xrow[64 + sub] = PK(g2, a0);   // cols 256..320 incl. zero pad
    Xrow[80 + sub]  = PK(g3, a1);
    Xrow[112 + sub] = PK(g4, a1);
    if (sub < 16) Xrow[144 + sub] = PK(g5, a1);  // cols 576..640 incl. zero pad
    Xrow[160 + sub] = PK(g6, a2);
    uint2 v;
    if (sub < 18)       v = PK(g7, a2);                                    // cols 768..840
    else if (sub == 24) v = make_uint2(pack2bf(a0, a1), pack2bf(a2, 0.f)); // cols 864..867
    else                v = make_uint2(0u, 0u);                            // pads
    Xrow[192 + sub] = v;
    #undef PK
}

// ---------------------------------------------------------------------------
// GEMM: out[M=16384, N=256] = Xg[M, K=896] (alpha-scaled bf16) @ W_ext[K, N].
// Block: 64 M x 128 N tile, 256 thr (4 waves, each 32Mx64N), BK=32, 28 iters.
// global_load_lds width-16 staging for A and B; grid 512.
// ---------------------------------------------------------------------------
__global__ __launch_bounds__(256, 4) void k_gemm(
    const ushort_t* __restrict__ Xg, const ushort_t* __restrict__ Wg,
    float* __restrict__ out)
{
    __shared__ __align__(16) ushort_t As[64 * 32];    // [row 64B][k-chunk]
    __shared__ __align__(16) ushort_t Bs[128 * 32];

    int tid = threadIdx.x, lane = tid & 63, w = tid >> 6;
    int mblk = (int)blockIdx.x >> 1, nblk = (int)blockIdx.x & 1;
    int tok0 = mblk * 64;

    // staging assignments (per wave: 1 A-instr + 2 B-instrs per K-iter)
    int ra = w * 16 + (lane >> 2);
    const ushort_t* gA = Xg + (size_t)(tok0 + ra) * KEXT + (lane & 3) * 8;
    ushort_t* lA  = As + w * 512 + lane * 8;
    ushort_t* lB0 = Bs + w * 512 + lane * 8;
    ushort_t* lB1 = Bs + (w + 4) * 512 + lane * 8;

    int m_off = (w & 1) * 32, n_off = (w >> 1) * 64;
    floatx4 acc[2][4];
    #pragma unroll
    for (int mt = 0; mt < 2; ++mt)
        #pragma unroll
        for (int nt = 0; nt < 4; ++nt) {
            floatx4 z = {0.f, 0.f, 0.f, 0.f};
            acc[mt][nt] = z;
        }

    for (int kc = 0; kc < 28; ++kc) {
        gload_lds16(gA + kc * 32, lA);
        const ushort_t* gBb = Wg + (((size_t)(nblk * 28 + kc) * 8) * 64 + lane) * 8;
        gload_lds16(gBb + (size_t)w * 512, lB0);
        gload_lds16(gBb + (size_t)(w + 4) * 512, lB1);
        __syncthreads();

        short8 aF[2], bF[4];
        #pragma unroll
        for (int mt = 0; mt < 2; ++mt)
            aF[mt] = *(const short8*)(As + (m_off + mt * 16 + (lane & 15)) * 32 + (lane >> 4) * 8);
        #pragma unroll
        for (int nt = 0; nt < 4; ++nt)
            bF[nt] = *(const short8*)(Bs + (n_off + nt * 16 + (lane & 15)) * 32 + (lane >> 4) * 8);
        #pragma unroll
        for (int mt = 0; mt < 2; ++mt)
            #pragma unroll
            for (int nt = 0; nt < 4; ++nt)
                acc[mt][nt] = __builtin_amdgcn_mfma_f32_16x16x32_bf16(aF[mt], bF[nt], acc[mt][nt], 0, 0, 0);
        __syncthreads();
    }

    // epilogue: bare store (bias folded into GEMM via alpha rows)
    #pragma unroll
    for (int mt = 0; mt < 2; ++mt) {
        #pragma unroll
        for (int r = 0; r < 4; ++r) {
            int tok = tok0 + m_off + mt * 16 + (lane >> 4) * 4 + r;
            size_t rowoff = (size_t)tok * DOUT + nblk * 128;
            #pragma unroll
            for (int nt = 0; nt < 4; ++nt)
                out[rowoff + n_off + nt * 16 + (lane & 15)] = acc[mt][nt][r];
        }
    }
}

extern "C" void kernel_launch(void* const* d_in, const int* in_sizes, int n_in,
                              void* d_out, int out_size, void* d_ws, size_t ws_size,
                              hipStream_t stream) {
    const int*   ids = (const int*)d_in[0];
    const float* E0  = (const float*)d_in[1];
    const float* E1  = (const float*)d_in[2];
    const float* E2  = (const float*)d_in[3];
    const float* W0  = (const float*)d_in[4];
    const float* b0  = (const float*)d_in[5];
    const float* W1  = (const float*)d_in[6];
    const float* b1  = (const float*)d_in[7];
    const float* W2  = (const float*)d_in[8];
    const float* b2  = (const float*)d_in[9];
    const float* Wa  = (const float*)d_in[10];
    const float* ba  = (const float*)d_in[11];

    float* u      = (float*)d_ws;                          // 896 floats (zero-padded)
    float* lb     = u + 896;                               // 3 floats
    ushort_t* Wg  = (ushort_t*)((char*)d_ws + 4096);       // 448 KB staging-linear B
    ushort_t* Xg  = (ushort_t*)((char*)d_ws + (512 << 10)); // 16384 x 896 bf16 = 28 MB

    k_prep<<<WG_BLKS + U_BLKS, 256, 0, stream>>>(W0, W1, W2, b0, b1, b2, Wa, ba,
                                                 u, lb, Wg);
    k_gather<<<NTOK / 8, 256, 0, stream>>>(ids, E0, E1, E2, u, lb, Xg);
    k_gemm<<<(NTOK / 64) * 2, 256, 0, stream>>>(Xg, Wg, (float*)d_out);
}